// Round 1
// baseline (215.651 us; speedup 1.0000x reference)
//
#include <hip/hip_runtime.h>
#include <hip/hip_bf16.h>
#include <stdint.h>

#define IN_CH 794
#define KPAD  832            // 26 * 32
#define Z1C   1024
#define OUT_C 512

typedef __attribute__((ext_vector_type(8))) short short8;
typedef __attribute__((ext_vector_type(4))) float f32x4;

__device__ __forceinline__ ushort f2bf(float f) {
  uint32_t u = __float_as_uint(f);
  return (ushort)((u + 0x7fffu + ((u >> 16) & 1u)) >> 16);  // RTNE
}

__device__ __forceinline__ void glds16(const void* g, void* l) {
  __builtin_amdgcn_global_load_lds(
      (const __attribute__((address_space(1))) void*)g,
      (__attribute__((address_space(3))) void*)l, 16, 0, 0);
}

// ---------------- prep: masked weights (bf16) + folded bias ----------------
__global__ __launch_bounds__(256) void prep1(
    const float* __restrict__ W1, const float* __restrict__ b1,
    const float* __restrict__ Wc1, const float* __restrict__ bc1,
    const float* __restrict__ MW0, ushort* __restrict__ w1p,
    float* __restrict__ bias1) {
  int z = blockIdx.x, t = threadIdx.x;
  float sum = 0.f;
  for (int i = t; i < KPAD; i += 256) {
    float w = 0.f;
    if (i < IN_CH) {
      float m = MW0[z * IN_CH + i];
      w = W1[z * IN_CH + i] * m;
      sum += Wc1[z * IN_CH + i] * m;
    }
    w1p[z * KPAD + i] = f2bf(w);
  }
#pragma unroll
  for (int o = 32; o > 0; o >>= 1) sum += __shfl_down(sum, o, 64);
  __shared__ float red[4];
  if ((t & 63) == 0) red[t >> 6] = sum;
  __syncthreads();
  if (t == 0) bias1[z] = b1[z] + bc1[z] + red[0] + red[1] + red[2] + red[3];
}

__global__ __launch_bounds__(256) void prep2(
    const float* __restrict__ W2, const float* __restrict__ b2,
    const float* __restrict__ Wc2, const float* __restrict__ bc2,
    const float* __restrict__ MW1, ushort* __restrict__ w2m,
    float* __restrict__ bias2) {
  int z = blockIdx.x, t = threadIdx.x;
  float sum = 0.f;
  for (int i = t; i < Z1C; i += 256) {
    float m = MW1[z * Z1C + i];
    w2m[z * Z1C + i] = f2bf(W2[z * Z1C + i] * m);
    sum += Wc2[z * Z1C + i] * m;
  }
#pragma unroll
  for (int o = 32; o > 0; o >>= 1) sum += __shfl_down(sum, o, 64);
  __shared__ float red[4];
  if ((t & 63) == 0) red[t >> 6] = sum;
  __syncthreads();
  if (t == 0) bias2[z] = b2[z] + bc2[z] + red[0] + red[1] + red[2] + red[3];
}

// ---------------- GEMM1: h1 = relu(x @ w1p^T + bias1), bf16 out ----------------
// 128x128 tile, BK=32, 4 waves (2x2), each wave 64x64 = 4x4 frags of 16x16x32.
__global__ __launch_bounds__(256, 2) void gemm1(
    const float* __restrict__ x, const ushort* __restrict__ w1p,
    const float* __restrict__ bias1, ushort* __restrict__ h1) {
  __shared__ ushort As[128 * 32];
  __shared__ ushort Bs[128 * 32];
  const int tid = threadIdx.x;
  const int lane = tid & 63, wid = tid >> 6;
  const int wr = wid >> 1, wc = wid & 1;
  const int brow = blockIdx.x * 128;
  const int bcol = blockIdx.y * 128;

  f32x4 acc[4][4] = {};

  const int arow = tid >> 1;            // 0..127
  const int acol0 = (tid & 1) * 16;     // 0 / 16
  const float* xrow = x + (size_t)(brow + arow) * IN_CH;

  for (int kt = 0; kt < 26; ++kt) {
    const int k0 = kt * 32;
    // --- B tile: global_load_lds (w1p is padded, always in-bounds) ---
#pragma unroll
    for (int c = 0; c < 2; ++c) {
      int idx16 = (wid * 2 + c) * 64 + lane;       // 16B-unit index
      int row = idx16 >> 2, chunk = idx16 & 3;
      glds16(w1p + (size_t)(bcol + row) * KPAD + k0 + chunk * 8,
             (char*)Bs + (wid * 2 + c) * 1024);
    }
    // --- A tile: f32 -> bf16 reg-stage ---
    union { ushort u[16]; uint4 q[2]; } pk;
    if (kt < 24) {
      const float* p = xrow + k0 + acol0;
#pragma unroll
      for (int j = 0; j < 8; ++j) {
        float2 v = *(const float2*)(p + j * 2);    // 8B-aligned always
        pk.u[j * 2] = f2bf(v.x);
        pk.u[j * 2 + 1] = f2bf(v.y);
      }
    } else {
#pragma unroll
      for (int j = 0; j < 16; ++j) {
        int col = k0 + acol0 + j;
        pk.u[j] = f2bf(col < IN_CH ? xrow[col] : 0.f);
      }
    }
    *(uint4*)&As[arow * 32 + acol0] = pk.q[0];
    *(uint4*)&As[arow * 32 + acol0 + 8] = pk.q[1];

    __syncthreads();
    const int kb = (lane >> 4) * 8, rA = lane & 15;
    short8 af[4], bfrag[4];
#pragma unroll
    for (int m = 0; m < 4; ++m)
      af[m] = *(const short8*)&As[(wr * 64 + m * 16 + rA) * 32 + kb];
#pragma unroll
    for (int n = 0; n < 4; ++n)
      bfrag[n] = *(const short8*)&Bs[(wc * 64 + n * 16 + rA) * 32 + kb];
#pragma unroll
    for (int m = 0; m < 4; ++m)
#pragma unroll
      for (int n = 0; n < 4; ++n)
        acc[m][n] = __builtin_amdgcn_mfma_f32_16x16x32_bf16(af[m], bfrag[n],
                                                            acc[m][n], 0, 0, 0);
    __syncthreads();
  }

  const int orow0 = brow + wr * 64;
  const int ocol0 = bcol + wc * 64;
#pragma unroll
  for (int n = 0; n < 4; ++n) {
    int col = ocol0 + n * 16 + (lane & 15);
    float bv = bias1[col];
#pragma unroll
    for (int m = 0; m < 4; ++m)
#pragma unroll
      for (int r = 0; r < 4; ++r) {
        int row = orow0 + m * 16 + (lane >> 4) * 4 + r;
        float v = acc[m][n][r] + bv;
        v = v > 0.f ? v : 0.f;
        h1[(size_t)row * Z1C + col] = f2bf(v);
      }
  }
}

// ---------------- GEMM2: out = relu(h1 @ w2m^T + bias2), f32, in-place over h1 ----------------
// grid over rows only (256 blocks x 128 rows); 8 waves (2x4), wave = 64x128 = 4x8 frags.
__global__ __launch_bounds__(512, 2) void gemm2(
    const ushort* __restrict__ h1, const ushort* __restrict__ w2m,
    const float* __restrict__ bias2, float* __restrict__ out) {
  __shared__ ushort As[128 * 32];
  __shared__ ushort Bs[512 * 32];
  const int tid = threadIdx.x;
  const int lane = tid & 63, wid = tid >> 6;
  const int wr = wid >> 2, wc = wid & 3;
  const int brow = blockIdx.x * 128;

  f32x4 acc[4][8] = {};

  for (int kt = 0; kt < 32; ++kt) {
    const int k0 = kt * 32;
    {  // A tile: 8KB, one glds per wave
      int idx16 = wid * 64 + lane;
      int row = idx16 >> 2, chunk = idx16 & 3;
      glds16(h1 + (size_t)(brow + row) * Z1C + k0 + chunk * 8,
             (char*)As + wid * 1024);
    }
#pragma unroll
    for (int c = 0; c < 4; ++c) {  // B tile: 32KB, 4 rounds
      int idx16 = c * 512 + wid * 64 + lane;
      int row = idx16 >> 2, chunk = idx16 & 3;
      glds16(w2m + (size_t)row * Z1C + k0 + chunk * 8,
             (char*)Bs + c * 8192 + wid * 1024);
    }
    __syncthreads();
    const int kb = (lane >> 4) * 8, rA = lane & 15;
    short8 af[4], bfrag[8];
#pragma unroll
    for (int m = 0; m < 4; ++m)
      af[m] = *(const short8*)&As[(wr * 64 + m * 16 + rA) * 32 + kb];
#pragma unroll
    for (int n = 0; n < 8; ++n)
      bfrag[n] = *(const short8*)&Bs[(wc * 128 + n * 16 + rA) * 32 + kb];
#pragma unroll
    for (int m = 0; m < 4; ++m)
#pragma unroll
      for (int n = 0; n < 8; ++n)
        acc[m][n] = __builtin_amdgcn_mfma_f32_16x16x32_bf16(af[m], bfrag[n],
                                                            acc[m][n], 0, 0, 0);
    __syncthreads();
  }

#pragma unroll
  for (int n = 0; n < 8; ++n) {
    int col = wc * 128 + n * 16 + (lane & 15);
    float bv = bias2[col];
#pragma unroll
    for (int m = 0; m < 4; ++m)
#pragma unroll
      for (int r = 0; r < 4; ++r) {
        int row = brow + wr * 64 + m * 16 + (lane >> 4) * 4 + r;
        float v = acc[m][n][r] + bv;
        out[(size_t)row * OUT_C + col] = v > 0.f ? v : 0.f;
      }
  }
}

extern "C" void kernel_launch(void* const* d_in, const int* in_sizes, int n_in,
                              void* d_out, int out_size, void* d_ws, size_t ws_size,
                              hipStream_t stream) {
  (void)in_sizes; (void)n_in; (void)out_size; (void)ws_size;
  const float* x   = (const float*)d_in[0];
  const float* W1  = (const float*)d_in[1];
  const float* b1  = (const float*)d_in[2];
  const float* Wc1 = (const float*)d_in[3];
  const float* bc1 = (const float*)d_in[4];
  const float* W2  = (const float*)d_in[5];
  const float* b2  = (const float*)d_in[6];
  const float* Wc2 = (const float*)d_in[7];
  const float* bc2 = (const float*)d_in[8];
  const float* MW0 = (const float*)d_in[9];
  const float* MW1 = (const float*)d_in[10];

  char* ws = (char*)d_ws;
  ushort* w1p  = (ushort*)ws;                    // 1024*832*2 = 1703936 B
  ushort* w2m  = (ushort*)(ws + 1703936);        // 512*1024*2 = 1048576 B
  float*  bias1 = (float*)(ws + 2752512);        // 1024*4
  float*  bias2 = (float*)(ws + 2756608);        // 512*4

  ushort* h1 = (ushort*)d_out;   // 32768x1024 bf16 aliases 32768x512 f32 exactly
  float*  out = (float*)d_out;

  prep1<<<1024, 256, 0, stream>>>(W1, b1, Wc1, bc1, MW0, w1p, bias1);
  prep2<<<512, 256, 0, stream>>>(W2, b2, Wc2, bc2, MW1, w2m, bias2);
  gemm1<<<dim3(256, 8), 256, 0, stream>>>(x, w1p, bias1, h1);
  gemm2<<<256, 512, 0, stream>>>(h1, w2m, bias2, out);
}

// Round 2
// 181.879 us; speedup vs baseline: 1.1857x; 1.1857x over previous
//
#include <hip/hip_runtime.h>
#include <hip/hip_bf16.h>
#include <stdint.h>

#define IN_CH 794
#define KPAD  832            // 26 * 32
#define Z1C   1024
#define OUT_C 512
#define BATCH 32768

typedef __attribute__((ext_vector_type(8))) short short8;
typedef __attribute__((ext_vector_type(4))) float f32x4;

__device__ __forceinline__ ushort f2bf(float f) {
  uint32_t u = __float_as_uint(f);
  return (ushort)((u + 0x7fffu + ((u >> 16) & 1u)) >> 16);  // RTNE
}

__device__ __forceinline__ void glds16(const void* g, void* l) {
  __builtin_amdgcn_global_load_lds(
      (const __attribute__((address_space(1))) void*)g,
      (__attribute__((address_space(3))) void*)l, 16, 0, 0);
}

// ---------------- prep: masked weights (bf16) + folded bias ----------------
__global__ __launch_bounds__(256) void prep1(
    const float* __restrict__ W1, const float* __restrict__ b1,
    const float* __restrict__ Wc1, const float* __restrict__ bc1,
    const float* __restrict__ MW0, ushort* __restrict__ w1p,
    float* __restrict__ bias1) {
  int z = blockIdx.x, t = threadIdx.x;
  float sum = 0.f;
  for (int i = t; i < KPAD; i += 256) {
    float w = 0.f;
    if (i < IN_CH) {
      float m = MW0[z * IN_CH + i];
      w = W1[z * IN_CH + i] * m;
      sum += Wc1[z * IN_CH + i] * m;
    }
    w1p[z * KPAD + i] = f2bf(w);
  }
#pragma unroll
  for (int o = 32; o > 0; o >>= 1) sum += __shfl_down(sum, o, 64);
  __shared__ float red[4];
  if ((t & 63) == 0) red[t >> 6] = sum;
  __syncthreads();
  if (t == 0) bias1[z] = b1[z] + bc1[z] + red[0] + red[1] + red[2] + red[3];
}

__global__ __launch_bounds__(256) void prep2(
    const float* __restrict__ W2, const float* __restrict__ b2,
    const float* __restrict__ Wc2, const float* __restrict__ bc2,
    const float* __restrict__ MW1, ushort* __restrict__ w2m,
    float* __restrict__ bias2) {
  int z = blockIdx.x, t = threadIdx.x;
  float sum = 0.f;
  for (int i = t; i < Z1C; i += 256) {
    float m = MW1[z * Z1C + i];
    w2m[z * Z1C + i] = f2bf(W2[z * Z1C + i] * m);
    sum += Wc2[z * Z1C + i] * m;
  }
#pragma unroll
  for (int o = 32; o > 0; o >>= 1) sum += __shfl_down(sum, o, 64);
  __shared__ float red[4];
  if ((t & 63) == 0) red[t >> 6] = sum;
  __syncthreads();
  if (t == 0) bias2[z] = b2[z] + bc2[z] + red[0] + red[1] + red[2] + red[3];
}

// ---------------- xcvt: x f32 [B,794] -> xb bf16 [B,832] (zero-padded) ----------------
__global__ __launch_bounds__(256) void xcvt(const float* __restrict__ x,
                                            ushort* __restrict__ xb) {
  const int CPR = KPAD / 8;  // 104 chunks of 8 per row
  const int total = BATCH * CPR;
  for (int i = blockIdx.x * 256 + threadIdx.x; i < total;
       i += gridDim.x * 256) {
    int row = i / CPR;
    int col = (i - row * CPR) * 8;
    const float* p = x + (size_t)row * IN_CH + col;
    ushort u[8];
    if (col + 8 <= IN_CH) {
#pragma unroll
      for (int j = 0; j < 4; ++j) {           // row base is 8B-aligned (794*4)
        float2 v = *(const float2*)(p + j * 2);
        u[j * 2] = f2bf(v.x);
        u[j * 2 + 1] = f2bf(v.y);
      }
    } else {
#pragma unroll
      for (int j = 0; j < 8; ++j) u[j] = (col + j < IN_CH) ? f2bf(p[j]) : 0;
    }
    *(uint4*)(xb + (size_t)row * KPAD + col) = *(uint4*)u;
  }
}

// ---------------- GEMM1 (pure m97): h1 = relu(xb @ w1p^T + bias1), bf16 out ----------------
// 128x128 tile, BK=32, 4 waves (2x2), wave 64x64 = 4x4 frags of 16x16x32.
__global__ __launch_bounds__(256, 2) void gemm1_pre(
    const ushort* __restrict__ xb, const ushort* __restrict__ w1p,
    const float* __restrict__ bias1, ushort* __restrict__ h1) {
  __shared__ ushort As[128 * 32];
  __shared__ ushort Bs[128 * 32];
  const int tid = threadIdx.x;
  const int lane = tid & 63, wid = tid >> 6;
  const int wr = wid >> 1, wc = wid & 1;
  const int bcol = blockIdx.x * 128;   // col fastest: 8 blocks share an A panel
  const int brow = blockIdx.y * 128;

  f32x4 acc[4][4] = {};

  for (int kt = 0; kt < 26; ++kt) {
    const int k0 = kt * 32;
#pragma unroll
    for (int c = 0; c < 2; ++c) {
      int idx16 = (wid * 2 + c) * 64 + lane;     // 16B-unit index
      int row = idx16 >> 2, chunk = idx16 & 3;   // 32 bf16/row = 4x16B
      glds16(xb + (size_t)(brow + row) * KPAD + k0 + chunk * 8,
             (char*)As + (wid * 2 + c) * 1024);
      glds16(w1p + (size_t)(bcol + row) * KPAD + k0 + chunk * 8,
             (char*)Bs + (wid * 2 + c) * 1024);
    }
    __syncthreads();
    const int kb = (lane >> 4) * 8, rA = lane & 15;
    short8 af[4], bfrag[4];
#pragma unroll
    for (int m = 0; m < 4; ++m)
      af[m] = *(const short8*)&As[(wr * 64 + m * 16 + rA) * 32 + kb];
#pragma unroll
    for (int n = 0; n < 4; ++n)
      bfrag[n] = *(const short8*)&Bs[(wc * 64 + n * 16 + rA) * 32 + kb];
#pragma unroll
    for (int m = 0; m < 4; ++m)
#pragma unroll
      for (int n = 0; n < 4; ++n)
        acc[m][n] = __builtin_amdgcn_mfma_f32_16x16x32_bf16(af[m], bfrag[n],
                                                            acc[m][n], 0, 0, 0);
    __syncthreads();
  }

  const int orow0 = brow + wr * 64;
  const int ocol0 = bcol + wc * 64;
#pragma unroll
  for (int n = 0; n < 4; ++n) {
    int col = ocol0 + n * 16 + (lane & 15);
    float bv = bias1[col];
#pragma unroll
    for (int m = 0; m < 4; ++m)
#pragma unroll
      for (int r = 0; r < 4; ++r) {
        int row = orow0 + m * 16 + (lane >> 4) * 4 + r;
        float v = acc[m][n][r] + bv;
        v = v > 0.f ? v : 0.f;
        h1[(size_t)row * Z1C + col] = f2bf(v);
      }
  }
}

// ---------------- GEMM1 fallback (fused conversion, round-1 version) ----------------
__global__ __launch_bounds__(256, 2) void gemm1_fused(
    const float* __restrict__ x, const ushort* __restrict__ w1p,
    const float* __restrict__ bias1, ushort* __restrict__ h1) {
  __shared__ ushort As[128 * 32];
  __shared__ ushort Bs[128 * 32];
  const int tid = threadIdx.x;
  const int lane = tid & 63, wid = tid >> 6;
  const int wr = wid >> 1, wc = wid & 1;
  const int brow = blockIdx.x * 128;
  const int bcol = blockIdx.y * 128;

  f32x4 acc[4][4] = {};

  const int arow = tid >> 1;
  const int acol0 = (tid & 1) * 16;
  const float* xrow = x + (size_t)(brow + arow) * IN_CH;

  for (int kt = 0; kt < 26; ++kt) {
    const int k0 = kt * 32;
#pragma unroll
    for (int c = 0; c < 2; ++c) {
      int idx16 = (wid * 2 + c) * 64 + lane;
      int row = idx16 >> 2, chunk = idx16 & 3;
      glds16(w1p + (size_t)(bcol + row) * KPAD + k0 + chunk * 8,
             (char*)Bs + (wid * 2 + c) * 1024);
    }
    union { ushort u[16]; uint4 q[2]; } pk;
    if (kt < 24) {
      const float* p = xrow + k0 + acol0;
#pragma unroll
      for (int j = 0; j < 8; ++j) {
        float2 v = *(const float2*)(p + j * 2);
        pk.u[j * 2] = f2bf(v.x);
        pk.u[j * 2 + 1] = f2bf(v.y);
      }
    } else {
#pragma unroll
      for (int j = 0; j < 16; ++j) {
        int col = k0 + acol0 + j;
        pk.u[j] = f2bf(col < IN_CH ? xrow[col] : 0.f);
      }
    }
    *(uint4*)&As[arow * 32 + acol0] = pk.q[0];
    *(uint4*)&As[arow * 32 + acol0 + 8] = pk.q[1];

    __syncthreads();
    const int kb = (lane >> 4) * 8, rA = lane & 15;
    short8 af[4], bfrag[4];
#pragma unroll
    for (int m = 0; m < 4; ++m)
      af[m] = *(const short8*)&As[(wr * 64 + m * 16 + rA) * 32 + kb];
#pragma unroll
    for (int n = 0; n < 4; ++n)
      bfrag[n] = *(const short8*)&Bs[(wc * 64 + n * 16 + rA) * 32 + kb];
#pragma unroll
    for (int m = 0; m < 4; ++m)
#pragma unroll
      for (int n = 0; n < 4; ++n)
        acc[m][n] = __builtin_amdgcn_mfma_f32_16x16x32_bf16(af[m], bfrag[n],
                                                            acc[m][n], 0, 0, 0);
    __syncthreads();
  }

  const int orow0 = brow + wr * 64;
  const int ocol0 = bcol + wc * 64;
#pragma unroll
  for (int n = 0; n < 4; ++n) {
    int col = ocol0 + n * 16 + (lane & 15);
    float bv = bias1[col];
#pragma unroll
    for (int m = 0; m < 4; ++m)
#pragma unroll
      for (int r = 0; r < 4; ++r) {
        int row = orow0 + m * 16 + (lane >> 4) * 4 + r;
        float v = acc[m][n][r] + bv;
        v = v > 0.f ? v : 0.f;
        h1[(size_t)row * Z1C + col] = f2bf(v);
      }
  }
}

// ---------------- GEMM2: out = relu(h1 @ w2m^T + bias2), f32, in-place over h1 ----------------
__global__ __launch_bounds__(512, 2) void gemm2(
    const ushort* __restrict__ h1, const ushort* __restrict__ w2m,
    const float* __restrict__ bias2, float* __restrict__ out) {
  __shared__ ushort As[128 * 32];
  __shared__ ushort Bs[512 * 32];
  const int tid = threadIdx.x;
  const int lane = tid & 63, wid = tid >> 6;
  const int wr = wid >> 2, wc = wid & 3;
  const int brow = blockIdx.x * 128;

  f32x4 acc[4][8] = {};

  for (int kt = 0; kt < 32; ++kt) {
    const int k0 = kt * 32;
    {
      int idx16 = wid * 64 + lane;
      int row = idx16 >> 2, chunk = idx16 & 3;
      glds16(h1 + (size_t)(brow + row) * Z1C + k0 + chunk * 8,
             (char*)As + wid * 1024);
    }
#pragma unroll
    for (int c = 0; c < 4; ++c) {
      int idx16 = c * 512 + wid * 64 + lane;
      int row = idx16 >> 2, chunk = idx16 & 3;
      glds16(w2m + (size_t)row * Z1C + k0 + chunk * 8,
             (char*)Bs + c * 8192 + wid * 1024);
    }
    __syncthreads();
    const int kb = (lane >> 4) * 8, rA = lane & 15;
    short8 af[4], bfrag[8];
#pragma unroll
    for (int m = 0; m < 4; ++m)
      af[m] = *(const short8*)&As[(wr * 64 + m * 16 + rA) * 32 + kb];
#pragma unroll
    for (int n = 0; n < 8; ++n)
      bfrag[n] = *(const short8*)&Bs[(wc * 128 + n * 16 + rA) * 32 + kb];
#pragma unroll
    for (int m = 0; m < 4; ++m)
#pragma unroll
      for (int n = 0; n < 8; ++n)
        acc[m][n] = __builtin_amdgcn_mfma_f32_16x16x32_bf16(af[m], bfrag[n],
                                                            acc[m][n], 0, 0, 0);
    __syncthreads();
  }

#pragma unroll
  for (int n = 0; n < 8; ++n) {
    int col = wc * 128 + n * 16 + (lane & 15);
    float bv = bias2[col];
#pragma unroll
    for (int m = 0; m < 4; ++m)
#pragma unroll
      for (int r = 0; r < 4; ++r) {
        int row = brow + wr * 64 + m * 16 + (lane >> 4) * 4 + r;
        float v = acc[m][n][r] + bv;
        out[(size_t)row * OUT_C + col] = v > 0.f ? v : 0.f;
      }
  }
}

extern "C" void kernel_launch(void* const* d_in, const int* in_sizes, int n_in,
                              void* d_out, int out_size, void* d_ws, size_t ws_size,
                              hipStream_t stream) {
  (void)in_sizes; (void)n_in; (void)out_size;
  const float* x   = (const float*)d_in[0];
  const float* W1  = (const float*)d_in[1];
  const float* b1  = (const float*)d_in[2];
  const float* Wc1 = (const float*)d_in[3];
  const float* bc1 = (const float*)d_in[4];
  const float* W2  = (const float*)d_in[5];
  const float* b2  = (const float*)d_in[6];
  const float* Wc2 = (const float*)d_in[7];
  const float* bc2 = (const float*)d_in[8];
  const float* MW0 = (const float*)d_in[9];
  const float* MW1 = (const float*)d_in[10];

  char* ws = (char*)d_ws;
  ushort* w1p   = (ushort*)ws;                   // 1024*832*2 = 1,703,936
  ushort* w2m   = (ushort*)(ws + 1703936);       //  512*1024*2 = 1,048,576
  float*  bias1 = (float*)(ws + 2752512);        // 4096
  float*  bias2 = (float*)(ws + 2756608);        // 2048
  ushort* xb    = (ushort*)(ws + 2758656);       // 32768*832*2 = 54,525,952
  const size_t WS_NEED = 2758656ull + 54525952ull;

  ushort* h1 = (ushort*)d_out;   // 32768x1024 bf16 aliases 32768x512 f32 exactly
  float*  out = (float*)d_out;

  prep1<<<1024, 256, 0, stream>>>(W1, b1, Wc1, bc1, MW0, w1p, bias1);
  prep2<<<512, 256, 0, stream>>>(W2, b2, Wc2, bc2, MW1, w2m, bias2);

  if (ws_size >= WS_NEED) {
    xcvt<<<2048, 256, 0, stream>>>(x, xb);
    gemm1_pre<<<dim3(8, 256), 256, 0, stream>>>(xb, w1p, bias1, h1);
  } else {
    gemm1_fused<<<dim3(256, 8), 256, 0, stream>>>(x, w1p, bias1, h1);
  }
  gemm2<<<256, 512, 0, stream>>>(h1, w2m, bias2, out);
}

// Round 3
// 140.064 us; speedup vs baseline: 1.5397x; 1.2985x over previous
//
#include <hip/hip_runtime.h>
#include <hip/hip_bf16.h>
#include <stdint.h>

#define IN_CH 794
#define KPAD  832            // 26 * 32 = 13 * 64
#define Z1C   1024
#define OUT_C 512
#define BATCH 32768

typedef __attribute__((ext_vector_type(8))) short short8;
typedef __attribute__((ext_vector_type(4))) float f32x4;

__device__ __forceinline__ ushort f2bf(float f) {
  uint32_t u = __float_as_uint(f);
  return (ushort)((u + 0x7fffu + ((u >> 16) & 1u)) >> 16);  // RTNE
}

__device__ __forceinline__ void glds16(const void* g, void* l) {
  __builtin_amdgcn_global_load_lds(
      (const __attribute__((address_space(1))) void*)g,
      (__attribute__((address_space(3))) void*)l, 16, 0, 0);
}

#define BAR() __builtin_amdgcn_s_barrier()
#define MFMA(a, b, c) __builtin_amdgcn_mfma_f32_16x16x32_bf16(a, b, c, 0, 0, 0)

// ---------------- prep: masked weights (bf16) + folded bias ----------------
__global__ __launch_bounds__(256) void prep1(
    const float* __restrict__ W1, const float* __restrict__ b1,
    const float* __restrict__ Wc1, const float* __restrict__ bc1,
    const float* __restrict__ MW0, ushort* __restrict__ w1p,
    float* __restrict__ bias1) {
  int z = blockIdx.x, t = threadIdx.x;
  float sum = 0.f;
  for (int i = t; i < KPAD; i += 256) {
    float w = 0.f;
    if (i < IN_CH) {
      float m = MW0[z * IN_CH + i];
      w = W1[z * IN_CH + i] * m;
      sum += Wc1[z * IN_CH + i] * m;
    }
    w1p[z * KPAD + i] = f2bf(w);
  }
#pragma unroll
  for (int o = 32; o > 0; o >>= 1) sum += __shfl_down(sum, o, 64);
  __shared__ float red[4];
  if ((t & 63) == 0) red[t >> 6] = sum;
  __syncthreads();
  if (t == 0) bias1[z] = b1[z] + bc1[z] + red[0] + red[1] + red[2] + red[3];
}

__global__ __launch_bounds__(256) void prep2(
    const float* __restrict__ W2, const float* __restrict__ b2,
    const float* __restrict__ Wc2, const float* __restrict__ bc2,
    const float* __restrict__ MW1, ushort* __restrict__ w2m,
    float* __restrict__ bias2) {
  int z = blockIdx.x, t = threadIdx.x;
  float sum = 0.f;
  for (int i = t; i < Z1C; i += 256) {
    float m = MW1[z * Z1C + i];
    w2m[z * Z1C + i] = f2bf(W2[z * Z1C + i] * m);
    sum += Wc2[z * Z1C + i] * m;
  }
#pragma unroll
  for (int o = 32; o > 0; o >>= 1) sum += __shfl_down(sum, o, 64);
  __shared__ float red[4];
  if ((t & 63) == 0) red[t >> 6] = sum;
  __syncthreads();
  if (t == 0) bias2[z] = b2[z] + bc2[z] + red[0] + red[1] + red[2] + red[3];
}

// ---------------- xcvt: x f32 [B,794] -> xb bf16 [B,832] (zero-padded) ----------------
__global__ __launch_bounds__(256) void xcvt(const float* __restrict__ x,
                                            ushort* __restrict__ xb) {
  const int CPR = KPAD / 8;  // 104 chunks of 8 per row
  const int total = BATCH * CPR;
  for (int i = blockIdx.x * 256 + threadIdx.x; i < total;
       i += gridDim.x * 256) {
    int row = i / CPR;
    int col = (i - row * CPR) * 8;
    const float* p = x + (size_t)row * IN_CH + col;
    ushort u[8];
    if (col + 8 <= IN_CH) {
#pragma unroll
      for (int j = 0; j < 4; ++j) {
        float2 v = *(const float2*)(p + j * 2);
        u[j * 2] = f2bf(v.x);
        u[j * 2 + 1] = f2bf(v.y);
      }
    } else {
#pragma unroll
      for (int j = 0; j < 8; ++j) u[j] = (col + j < IN_CH) ? f2bf(p[j]) : 0;
    }
    *(uint4*)(xb + (size_t)row * KPAD + col) = *(uint4*)u;
  }
}

// =================== 8-phase-style pipelined GEMM (T1+T2+T3+T4+T5) ===================
// C[M,N] = relu(A[M,KP] @ B[N,KP]^T + bias), A,B bf16 (ushort), K = NKT*64.
// BM=256, BN=128, BK=64, 512 thr (8 waves 4Mx2N), wave tile 64x64 (acc 4x4 frags).
// LDS: 3 bufs x 48KB (A 256x64 + B 128x64, XOR-swizzled); per K-tile 4 phases,
// each: ds_read quadrant frags | 1 prefetch chunk (tile j+2) | BAR | prio1 |
// 8 MFMA | prio0 | BAR.  vmcnt(6) once per K-tile (never 0 in steady state).
template <int KP, int NKT, int NCB, int OSTR, bool BF16OUT>
__global__ __launch_bounds__(512, 2) void gemm8(
    const ushort* __restrict__ Ag, const ushort* __restrict__ Bg,
    const float* __restrict__ bias, void* __restrict__ Cout) {
  __shared__ ushort lds[73728];  // 144 KB
  char* const L = (char*)lds;
  const int tid = threadIdx.x;
  const int lane = tid & 63, wid = tid >> 6;
  const int wr = wid >> 1, wc = wid & 1;

  // T1: bijective XCD chunk swizzle (nwg % 8 == 0 for both instantiations)
  const int nwg = gridDim.x;
  const int w0 = blockIdx.x;
  const int swz = (w0 & 7) * (nwg >> 3) + (w0 >> 3);
  const int bcol = (swz % NCB) * 128;
  const int brow = (swz / NCB) * 256;

  // ---- staging source offsets (pre-swizzled global, rule #21) ----
  const int ra0 = tid >> 3;            // rows 0..63   (A chunk c=0)
  const int ra1 = 64 + (tid >> 3);     // rows 64..127 (A chunk c=1)
  const int cbs = (tid & 7) * 16;
  const size_t gA0 = (size_t)(brow + ra0) * (KP * 2) + (cbs ^ ((ra0 & 7) << 4));
  const size_t gA1 = (size_t)(brow + ra1) * (KP * 2) + (cbs ^ ((ra1 & 7) << 4));
  const int rb = tid >> 3;             // 0..63
  const size_t gB = (size_t)(bcol + rb) * (KP * 2) + (cbs ^ ((rb & 7) << 4));

  // stage chunk of K-tile kt into buffer bufp
  auto stA0 = [&](char* bufp, int kt, int h) {
    glds16((const char*)Ag + gA0 + (size_t)h * (128 * KP * 2) + (size_t)kt * 128,
           bufp + h * 16384 + wid * 1024);
  };
  auto stA1 = [&](char* bufp, int kt, int h) {
    glds16((const char*)Ag + gA1 + (size_t)h * (128 * KP * 2) + (size_t)kt * 128,
           bufp + h * 16384 + 8192 + wid * 1024);
  };
  auto stB = [&](char* bufp, int kt, int h) {
    glds16((const char*)Bg + gB + (size_t)h * (64 * KP * 2) + (size_t)kt * 128,
           bufp + 32768 + h * 8192 + wid * 1024);
  };

  // ---- fragment read offsets (swizzled ds_read_b128) ----
  const int rA = lane & 15;
  const int klo = (lane >> 4) * 16;          // byte within K-slice
  const int xs = (rA & 7) << 4;              // XOR swizzle term

  f32x4 acc[4][4] = {};

  // prologue: stage K-tiles 0 (buf0) and 1 (buf1)
  {
    char* b0 = L;
    stA0(b0, 0, 0); stA1(b0, 0, 0); stA0(b0, 0, 1); stA1(b0, 0, 1);
    stB(b0, 0, 0); stB(b0, 0, 1);
    char* b1 = L + 49152;
    stA0(b1, 1, 0); stA1(b1, 1, 0); stA0(b1, 1, 1); stA1(b1, 1, 1);
    stB(b1, 1, 0); stB(b1, 1, 1);
  }
  asm volatile("s_waitcnt vmcnt(6)" ::: "memory");  // K-tile 0 complete
  BAR();

  for (int j = 0; j < NKT; ++j) {
    char* const Lb = L + (j % 3) * 49152;
    const bool pf = (j + 2 < NKT);
    char* const L2 = L + ((j + 2) % 3) * 49152;
    const int j2 = j + 2;

    auto rdA = [&](int m, int ks) -> short8 {
      int lrow = (wr & 1) * 64 + m * 16 + rA;
      return *(const short8*)(Lb + (wr >> 1) * 16384 + lrow * 128 +
                              ((ks * 64 + klo) ^ xs));
    };
    auto rdB = [&](int n, int ks) -> short8 {
      return *(const short8*)(Lb + 32768 + wc * 8192 + (n * 16 + rA) * 128 +
                              ((ks * 64 + klo) ^ xs));
    };

    // ---- phase 0: quadrant (m0-1, n0-1) ----
    short8 a0k0 = rdA(0, 0), a0k1 = rdA(0, 1);
    short8 a1k0 = rdA(1, 0), a1k1 = rdA(1, 1);
    short8 b0k0 = rdB(0, 0), b0k1 = rdB(0, 1);
    short8 b1k0 = rdB(1, 0), b1k1 = rdB(1, 1);
    if (pf) { stA0(L2, j2, 0); stA1(L2, j2, 0); }
    BAR();
    __builtin_amdgcn_s_setprio(1);
    acc[0][0] = MFMA(a0k0, b0k0, acc[0][0]); acc[0][0] = MFMA(a0k1, b0k1, acc[0][0]);
    acc[0][1] = MFMA(a0k0, b1k0, acc[0][1]); acc[0][1] = MFMA(a0k1, b1k1, acc[0][1]);
    acc[1][0] = MFMA(a1k0, b0k0, acc[1][0]); acc[1][0] = MFMA(a1k1, b0k1, acc[1][0]);
    acc[1][1] = MFMA(a1k0, b1k0, acc[1][1]); acc[1][1] = MFMA(a1k1, b1k1, acc[1][1]);
    __builtin_amdgcn_s_setprio(0);
    BAR();

    // ---- phase 1: quadrant (m0-1, n2-3) ----
    short8 b2k0 = rdB(2, 0), b2k1 = rdB(2, 1);
    short8 b3k0 = rdB(3, 0), b3k1 = rdB(3, 1);
    if (pf) { stA0(L2, j2, 1); stA1(L2, j2, 1); }
    BAR();
    __builtin_amdgcn_s_setprio(1);
    acc[0][2] = MFMA(a0k0, b2k0, acc[0][2]); acc[0][2] = MFMA(a0k1, b2k1, acc[0][2]);
    acc[0][3] = MFMA(a0k0, b3k0, acc[0][3]); acc[0][3] = MFMA(a0k1, b3k1, acc[0][3]);
    acc[1][2] = MFMA(a1k0, b2k0, acc[1][2]); acc[1][2] = MFMA(a1k1, b2k1, acc[1][2]);
    acc[1][3] = MFMA(a1k0, b3k0, acc[1][3]); acc[1][3] = MFMA(a1k1, b3k1, acc[1][3]);
    __builtin_amdgcn_s_setprio(0);
    BAR();

    // ---- phase 2: quadrant (m2-3, n0-1) ----
    short8 a2k0 = rdA(2, 0), a2k1 = rdA(2, 1);
    short8 a3k0 = rdA(3, 0), a3k1 = rdA(3, 1);
    if (pf) stB(L2, j2, 0);
    BAR();
    __builtin_amdgcn_s_setprio(1);
    acc[2][0] = MFMA(a2k0, b0k0, acc[2][0]); acc[2][0] = MFMA(a2k1, b0k1, acc[2][0]);
    acc[2][1] = MFMA(a2k0, b1k0, acc[2][1]); acc[2][1] = MFMA(a2k1, b1k1, acc[2][1]);
    acc[3][0] = MFMA(a3k0, b0k0, acc[3][0]); acc[3][0] = MFMA(a3k1, b0k1, acc[3][0]);
    acc[3][1] = MFMA(a3k0, b1k0, acc[3][1]); acc[3][1] = MFMA(a3k1, b1k1, acc[3][1]);
    __builtin_amdgcn_s_setprio(0);
    BAR();

    // ---- phase 3: quadrant (m2-3, n2-3) ----
    if (pf) {
      stB(L2, j2, 1);
      asm volatile("s_waitcnt vmcnt(6)" ::: "memory");  // K-tile j+1 ready
    } else if (j + 1 < NKT) {
      asm volatile("s_waitcnt vmcnt(0)" ::: "memory");
    }
    BAR();
    __builtin_amdgcn_s_setprio(1);
    acc[2][2] = MFMA(a2k0, b2k0, acc[2][2]); acc[2][2] = MFMA(a2k1, b2k1, acc[2][2]);
    acc[2][3] = MFMA(a2k0, b3k0, acc[2][3]); acc[2][3] = MFMA(a2k1, b3k1, acc[2][3]);
    acc[3][2] = MFMA(a3k0, b2k0, acc[3][2]); acc[3][2] = MFMA(a3k1, b2k1, acc[3][2]);
    acc[3][3] = MFMA(a3k0, b3k0, acc[3][3]); acc[3][3] = MFMA(a3k1, b3k1, acc[3][3]);
    __builtin_amdgcn_s_setprio(0);
    BAR();
  }

  // ---- epilogue ----
#pragma unroll
  for (int n = 0; n < 4; ++n) {
    const int col = bcol + wc * 64 + n * 16 + rA;
    const float bv = bias[col];
#pragma unroll
    for (int m = 0; m < 4; ++m) {
#pragma unroll
      for (int r = 0; r < 4; ++r) {
        const int row = brow + wr * 64 + m * 16 + (lane >> 4) * 4 + r;
        float v = acc[m][n][r] + bv;
        v = v > 0.f ? v : 0.f;
        if (BF16OUT)
          ((ushort*)Cout)[(size_t)row * OSTR + col] = f2bf(v);
        else
          ((float*)Cout)[(size_t)row * OSTR + col] = v;
      }
    }
  }
}

// ---------------- GEMM1 fallback (fused conversion, round-1 proven) ----------------
__global__ __launch_bounds__(256, 2) void gemm1_fused(
    const float* __restrict__ x, const ushort* __restrict__ w1p,
    const float* __restrict__ bias1, ushort* __restrict__ h1) {
  __shared__ ushort As[128 * 32];
  __shared__ ushort Bs[128 * 32];
  const int tid = threadIdx.x;
  const int lane = tid & 63, wid = tid >> 6;
  const int wr = wid >> 1, wc = wid & 1;
  const int brow = blockIdx.x * 128;
  const int bcol = blockIdx.y * 128;

  f32x4 acc[4][4] = {};
  const int arow = tid >> 1;
  const int acol0 = (tid & 1) * 16;
  const float* xrow = x + (size_t)(brow + arow) * IN_CH;

  for (int kt = 0; kt < 26; ++kt) {
    const int k0 = kt * 32;
#pragma unroll
    for (int c = 0; c < 2; ++c) {
      int idx16 = (wid * 2 + c) * 64 + lane;
      int row = idx16 >> 2, chunk = idx16 & 3;
      glds16(w1p + (size_t)(bcol + row) * KPAD + k0 + chunk * 8,
             (char*)Bs + (wid * 2 + c) * 1024);
    }
    union { ushort u[16]; uint4 q[2]; } pk;
    if (kt < 24) {
      const float* p = xrow + k0 + acol0;
#pragma unroll
      for (int j = 0; j < 8; ++j) {
        float2 v = *(const float2*)(p + j * 2);
        pk.u[j * 2] = f2bf(v.x);
        pk.u[j * 2 + 1] = f2bf(v.y);
      }
    } else {
#pragma unroll
      for (int j = 0; j < 16; ++j) {
        int col = k0 + acol0 + j;
        pk.u[j] = f2bf(col < IN_CH ? xrow[col] : 0.f);
      }
    }
    *(uint4*)&As[arow * 32 + acol0] = pk.q[0];
    *(uint4*)&As[arow * 32 + acol0 + 8] = pk.q[1];

    __syncthreads();
    const int kb = (lane >> 4) * 8, rA = lane & 15;
    short8 af[4], bfrag[4];
#pragma unroll
    for (int m = 0; m < 4; ++m)
      af[m] = *(const short8*)&As[(wr * 64 + m * 16 + rA) * 32 + kb];
#pragma unroll
    for (int n = 0; n < 4; ++n)
      bfrag[n] = *(const short8*)&Bs[(wc * 64 + n * 16 + rA) * 32 + kb];
#pragma unroll
    for (int m = 0; m < 4; ++m)
#pragma unroll
      for (int n = 0; n < 4; ++n)
        acc[m][n] = MFMA(af[m], bfrag[n], acc[m][n]);
    __syncthreads();
  }

  const int orow0 = brow + wr * 64;
  const int ocol0 = bcol + wc * 64;
#pragma unroll
  for (int n = 0; n < 4; ++n) {
    int col = ocol0 + n * 16 + (lane & 15);
    float bv = bias1[col];
#pragma unroll
    for (int m = 0; m < 4; ++m)
#pragma unroll
      for (int r = 0; r < 4; ++r) {
        int row = orow0 + m * 16 + (lane >> 4) * 4 + r;
        float v = acc[m][n][r] + bv;
        v = v > 0.f ? v : 0.f;
        h1[(size_t)row * Z1C + col] = f2bf(v);
      }
  }
}

extern "C" void kernel_launch(void* const* d_in, const int* in_sizes, int n_in,
                              void* d_out, int out_size, void* d_ws, size_t ws_size,
                              hipStream_t stream) {
  (void)in_sizes; (void)n_in; (void)out_size;
  const float* x   = (const float*)d_in[0];
  const float* W1  = (const float*)d_in[1];
  const float* b1  = (const float*)d_in[2];
  const float* Wc1 = (const float*)d_in[3];
  const float* bc1 = (const float*)d_in[4];
  const float* W2  = (const float*)d_in[5];
  const float* b2  = (const float*)d_in[6];
  const float* Wc2 = (const float*)d_in[7];
  const float* bc2 = (const float*)d_in[8];
  const float* MW0 = (const float*)d_in[9];
  const float* MW1 = (const float*)d_in[10];

  char* ws = (char*)d_ws;
  ushort* w1p   = (ushort*)ws;                   // 1024*832*2 = 1,703,936
  ushort* w2m   = (ushort*)(ws + 1703936);       //  512*1024*2 = 1,048,576
  float*  bias1 = (float*)(ws + 2752512);        // 4096
  float*  bias2 = (float*)(ws + 2756608);        // 2048
  ushort* xb    = (ushort*)(ws + 2758656);       // 32768*832*2 = 54,525,952
  const size_t WS_NEED = 2758656ull + 54525952ull;

  ushort* h1 = (ushort*)d_out;   // 32768x1024 bf16 aliases 32768x512 f32 exactly
  float*  out = (float*)d_out;

  prep1<<<1024, 256, 0, stream>>>(W1, b1, Wc1, bc1, MW0, w1p, bias1);
  prep2<<<512, 256, 0, stream>>>(W2, b2, Wc2, bc2, MW1, w2m, bias2);

  if (ws_size >= WS_NEED) {
    xcvt<<<2048, 256, 0, stream>>>(x, xb);
    // M=32768 (128 row blocks), N=1024 (8 col blocks), K=832 (13 K-tiles)
    gemm8<KPAD, 13, 8, Z1C, true><<<1024, 512, 0, stream>>>(xb, w1p, bias1, h1);
  } else {
    gemm1_fused<<<dim3(256, 8), 256, 0, stream>>>(x, w1p, bias1, h1);
  }
  // M=32768 (128 row blocks), N=512 (4 col blocks), K=1024 (16 K-tiles)
  gemm8<Z1C, 16, 4, OUT_C, false><<<512, 512, 0, stream>>>(h1, w2m, bias2, out);
}